// Round 6
// baseline (1125.729 us; speedup 1.0000x reference)
//
#include <hip/hip_runtime.h>

#define LDIM 50
#define MBIN 262144
#define ODIM 155
#define VOCABSZ 100

// workspace layout (floats) — produced by precompute_kernel
#define WS_T  0        // 6*100*50 = 30000 : T[s][v][d], s=0 pe-slot (b_pred folded), s=1..5 ve-slots
#define WS_TB 30000    // 100*50 : oe[v] @ W_bin[50:100] + b_bin
#define WS_LG 35000    // 300 : attention logits  [0..99]=pe, [100..199]=ve, [200..299]=oe

// static-LDS layout (floats) for fused kernel
#define O_T   0        // 30000 : T tables              (phase3: reused for store-transpose)
#define O_PE  30000    // 5000  : pe                    (phase2: reused for Tb)
#define O_VE  35000    // 5000  : ve                    (phase2: reused for oe)
#define O_LG  40000    // 304   : attention logits
#define LDS_FLOATS 40304   // 161216 B static

// ---------------------------------------------------------------------------
// Precompute vocab-indexed tables (trivial cost, ~2 MFLOP)
// ---------------------------------------------------------------------------
__global__ __launch_bounds__(64) void precompute_kernel(
    const float* __restrict__ pe, const float* __restrict__ ve, const float* __restrict__ oe,
    const float* __restrict__ W_pred, const float* __restrict__ b_pred,
    const float* __restrict__ W_bin, const float* __restrict__ b_bin,
    const float* __restrict__ W_att, const float* __restrict__ b_att,
    float* __restrict__ ws)
{
    const int bid = blockIdx.x;
    const int t = threadIdx.x;
    if (bid < 600) {
        const int s = bid / VOCABSZ, v = bid % VOCABSZ;
        if (t < LDIM) {
            const float* E = (s == 0) ? pe : ve;
            float acc = (s == 0) ? b_pred[t] : 0.0f;
            for (int e = 0; e < LDIM; ++e)
                acc += E[v*LDIM + e] * W_pred[(s*LDIM + e)*LDIM + t];
            ws[WS_T + (s*VOCABSZ + v)*LDIM + t] = acc;
        }
    } else if (bid < 700) {
        const int v = bid - 600;
        if (t < LDIM) {
            float acc = b_bin[t];
            for (int e = 0; e < LDIM; ++e)
                acc += oe[v*LDIM + e] * W_bin[(LDIM + e)*LDIM + t];
            ws[WS_TB + v*LDIM + t] = acc;
        }
    } else {
        const int g = (bid - 700)*64 + t;
        if (g < 300) {
            const int which = g / VOCABSZ, v = g % VOCABSZ;
            const float* E = (which == 0) ? pe : ((which == 1) ? ve : oe);
            float acc = b_att[0];
            for (int e = 0; e < LDIM; ++e)
                acc += E[v*LDIM + e] * W_att[e];
            ws[WS_LG + g] = acc;
        }
    }
}

// ---------------------------------------------------------------------------
// Pass 1 (logit): build pred node, keep ONLY the attention logit.
// Live set: a handful of temps — no h[] storage. Returns exp(h.W_att + b_att).
// ---------------------------------------------------------------------------
__device__ __forceinline__ float pred_logit_lds(
    int p, const int* v, const float* __restrict__ lds,
    const float* __restrict__ W_att, float batt)
{
    const float* lg = lds + O_LG;
    const float e0 = __expf(lg[p]);
    float ek[5];
    float den = e0;
#pragma unroll
    for (int s = 0; s < 5; ++s) { ek[s] = __expf(lg[VOCABSZ + v[s]]); den += ek[s]; }
    const float inv = 1.0f / den;

    const float2* T2  = reinterpret_cast<const float2*>(lds + O_T);
    const float2* pe2 = reinterpret_cast<const float2*>(lds + O_PE);
    const float2* ve2 = reinterpret_cast<const float2*>(lds + O_VE);
    const int rT0 = p*(LDIM/2);
    int rTs[5], rVs[5];
#pragma unroll
    for (int s = 0; s < 5; ++s) {
        rTs[s] = ((s+1)*VOCABSZ + v[s])*(LDIM/2);
        rVs[s] = v[s]*(LDIM/2);
    }

    float l = batt;
    for (int i = 0; i < LDIM/2; ++i) {
        float2 lin = T2[rT0 + i];
        float2 pv  = pe2[rT0 + i];
        float nx = e0*pv.x, ny = e0*pv.y;
#pragma unroll
        for (int s = 0; s < 5; ++s) {
            float2 a = T2[rTs[s] + i];
            float2 b = ve2[rVs[s] + i];
            lin.x += a.x; lin.y += a.y;
            nx += ek[s]*b.x; ny += ek[s]*b.y;
        }
        const float hx = fmaxf(lin.x, 0.0f) + nx*inv;
        const float hy = fmaxf(lin.y, 0.0f) + ny*inv;
        l += hx*W_att[2*i] + hy*W_att[2*i+1];
    }
    return __expf(l);
}

// ---------------------------------------------------------------------------
// Pass 2 (stream): rebuild pred node, consuming each element the moment it is
// produced:  lin2[d'] += h[e]*Wop[e][d']  and  num[e] += w*h[e].
// w known from pass 1 -> h[] never materialized.
// Peak live: lin2[50]+num[50]+temps ~ 110 -> fits the allocator's hard
// 128-VGPR choice at 512-thr with NO spills.
// (i-loop fully unrolled: num[2i] needs compile-time indices.)
// ---------------------------------------------------------------------------
__device__ __forceinline__ void pred_stream_lds(
    int p, const int* v, const float* __restrict__ lds, float w,
    const float* __restrict__ Wop,   // 50 rows x 50 (wave-uniform -> s_load stream)
    float* __restrict__ lin2, float* __restrict__ num)
{
    const float* lg = lds + O_LG;
    const float e0 = __expf(lg[p]);
    float ek[5];
    float den = e0;
#pragma unroll
    for (int s = 0; s < 5; ++s) { ek[s] = __expf(lg[VOCABSZ + v[s]]); den += ek[s]; }
    const float inv = 1.0f / den;

    const float2* T2  = reinterpret_cast<const float2*>(lds + O_T);
    const float2* pe2 = reinterpret_cast<const float2*>(lds + O_PE);
    const float2* ve2 = reinterpret_cast<const float2*>(lds + O_VE);
    const int rT0 = p*(LDIM/2);
    int rTs[5], rVs[5];
#pragma unroll
    for (int s = 0; s < 5; ++s) {
        rTs[s] = ((s+1)*VOCABSZ + v[s])*(LDIM/2);
        rVs[s] = v[s]*(LDIM/2);
    }

#pragma unroll
    for (int i = 0; i < LDIM/2; ++i) {
        float2 lin = T2[rT0 + i];
        float2 pv  = pe2[rT0 + i];
        float nx = e0*pv.x, ny = e0*pv.y;
#pragma unroll
        for (int s = 0; s < 5; ++s) {
            float2 a = T2[rTs[s] + i];
            float2 b = ve2[rVs[s] + i];
            lin.x += a.x; lin.y += a.y;
            nx += ek[s]*b.x; ny += ek[s]*b.y;
        }
        const float hx = fmaxf(lin.x, 0.0f) + nx*inv;
        const float hy = fmaxf(lin.y, 0.0f) + ny*inv;
        num[2*i]   += w*hx;
        num[2*i+1] += w*hy;
        const float* wr0 = Wop + (2*i)*LDIM;
        const float* wr1 = Wop + (2*i+1)*LDIM;
#pragma unroll
        for (int d = 0; d < LDIM; ++d) lin2[d] += hx*wr0[d] + hy*wr1[d];
    }
}

// ---------------------------------------------------------------------------
// Fused kernel: one thread per binary node; 512-thr (the only block size where
// the allocator picks 128 VGPRs). Static fp32 LDS (161216 B, 1 block/CU).
// Phase 1 = logit pass + streaming pass: peak live ~110 floats -> NO spills.
// (Round-5 bug: pe/ve/oe staging loops were accidentally dropped -> garbage
//  reads. Restored verbatim from round 0 here; everything else unchanged.)
// LDS lifecycle: [T|pe|ve|lg] -> phase2 overwrites pe/ve with [Tb|oe] ->
// phase3 reuses T region for per-wave store transpose.
// ---------------------------------------------------------------------------
__global__ __launch_bounds__(512)
void fused_kernel(
    const float* __restrict__ pe, const float* __restrict__ ve, const float* __restrict__ oe,
    const float* __restrict__ W_bin,
    const float* __restrict__ W_un, const float* __restrict__ b_un,
    const float* __restrict__ W_univ, const float* __restrict__ b_univ,
    const float* __restrict__ W_att, const float* __restrict__ b_att,
    const float* __restrict__ W_fin, const float* __restrict__ b_fin,
    const int* __restrict__ pred_ids, const int* __restrict__ var_ids,
    const int* __restrict__ op_ids,
    const float* __restrict__ ws, float* __restrict__ out)
{
    __shared__ float lds[LDS_FLOATS];
    const int tid = threadIdx.x;
    const int j = blockIdx.x * 512 + tid;

    // ---- stage T + pe + ve + lg into LDS (coalesced float4) ----
    {
        const float4* src = reinterpret_cast<const float4*>(ws + WS_T);     // 7500 vec4
        float4* dst = reinterpret_cast<float4*>(lds + O_T);
        for (int i = tid; i < 7500; i += 512) dst[i] = src[i];
        const float4* s2 = reinterpret_cast<const float4*>(pe);             // 1250
        float4* d2 = reinterpret_cast<float4*>(lds + O_PE);
        for (int i = tid; i < 1250; i += 512) d2[i] = s2[i];
        const float4* s3 = reinterpret_cast<const float4*>(ve);
        float4* d3 = reinterpret_cast<float4*>(lds + O_VE);
        for (int i = tid; i < 1250; i += 512) d3[i] = s3[i];
        if (tid < 300) lds[O_LG + tid] = ws[WS_LG + tid];
    }
    __syncthreads();

    const float batt = b_att[0];

    int vA[5], vB[5];
    const int pA = pred_ids[2*j], pB = pred_ids[2*j+1];
#pragma unroll
    for (int s = 0; s < 5; ++s) { vA[s] = var_ids[(2*j)*5 + s]; vB[s] = var_ids[(2*j+1)*5 + s]; }
    const int op = op_ids[j];

    // ---- phase 1a: attention logits only (no h storage) ----
    const float w0 = pred_logit_lds(pA, vA, lds, W_att, batt);
    const float w2 = pred_logit_lds(pB, vB, lds, W_att, batt);
    const float w1 = __expf(lds[O_LG + 2*VOCABSZ + op]);
    const float inv2 = 1.0f / (w0 + w1 + w2);

    // ---- phase 1b: rebuild both nodes, streaming into lin2/num ----
    float lin2[LDIM], num[LDIM];
#pragma unroll
    for (int d = 0; d < LDIM; ++d) { lin2[d] = 0.0f; num[d] = 0.0f; }
    pred_stream_lds(pA, vA, lds, w0, W_bin, lin2, num);
    pred_stream_lds(pB, vB, lds, w2, W_bin + 2*LDIM*LDIM, lin2, num);

    __syncthreads();   // all phase-1 LDS reads done

    // ---- stage Tb + oe into the (dead) pe/ve region ----
    {
        const float4* src = reinterpret_cast<const float4*>(ws + WS_TB);    // 1250 vec4
        float4* dst = reinterpret_cast<float4*>(lds + O_PE);
        for (int i = tid; i < 1250; i += 512) dst[i] = src[i];
        const float4* s2 = reinterpret_cast<const float4*>(oe);
        float4* d2 = reinterpret_cast<float4*>(lds + O_VE);
        for (int i = tid; i < 1250; i += 512) d2[i] = s2[i];
    }
    __syncthreads();

    // ---- h_bin = relu(lin2 + Tb[op]) + (num + w1*oe[op]) * inv2 ----
    float h[LDIM];
    {
        const float2* Tb2 = reinterpret_cast<const float2*>(lds + O_PE);
        const float2* oe2 = reinterpret_cast<const float2*>(lds + O_VE);
        const int r = op*(LDIM/2);
#pragma unroll
        for (int i = 0; i < LDIM/2; ++i) {
            float2 t2 = Tb2[r+i];
            float2 o2 = oe2[r+i];
            h[2*i]   = fmaxf(lin2[2*i]   + t2.x, 0.0f) + (num[2*i]   + w1*o2.x)*inv2;
            h[2*i+1] = fmaxf(lin2[2*i+1] + t2.y, 0.0f) + (num[2*i+1] + w1*o2.y)*inv2;
        }
    }

    // ---- h_un = relu(h @ W_un + b_un); h_q = relu(h_un @ W_univ + b_univ) ----
    {
        float acc[LDIM];
#pragma unroll
        for (int d = 0; d < LDIM; ++d) acc[d] = b_un[d];
#pragma unroll
        for (int e = 0; e < LDIM; ++e) {
            const float he = h[e];
            const float* wr = W_un + e*LDIM;
#pragma unroll
            for (int d = 0; d < LDIM; ++d) acc[d] += he * wr[d];
        }
#pragma unroll
        for (int d = 0; d < LDIM; ++d) h[d] = fmaxf(acc[d], 0.0f);
    }
    {
        float acc[LDIM];
#pragma unroll
        for (int d = 0; d < LDIM; ++d) acc[d] = b_univ[d];
#pragma unroll
        for (int e = 0; e < LDIM; ++e) {
            const float he = h[e];
            const float* wr = W_univ + e*LDIM;
#pragma unroll
            for (int d = 0; d < LDIM; ++d) acc[d] += he * wr[d];
        }
#pragma unroll
        for (int d = 0; d < LDIM; ++d) h[d] = fmaxf(acc[d], 0.0f);
    }

    // ---- phase 3: out row = h @ W_fin + b_fin, LDS-transposed coalesced stores
    //      (per-wave buffer in the dead T region; wave-synchronous, no barrier;
    //       8 waves * 2112 = 16896 floats < 30000-float T region)
    const int wave = tid >> 6, lane = tid & 63;
    float* sw = lds + O_T + wave * (64*33);
    const int rowbase = blockIdx.x*512 + wave*64;
    for (int c = 0; c < 5; ++c) {
        float acc[31];
        const int obase = c * 31;
#pragma unroll
        for (int o = 0; o < 31; ++o) acc[o] = b_fin[obase + o];
#pragma unroll
        for (int d = 0; d < LDIM; ++d) {
            const float hq = h[d];
            const float* wr = W_fin + d*ODIM + obase;
#pragma unroll
            for (int o = 0; o < 31; ++o) acc[o] += hq * wr[o];
        }
#pragma unroll
        for (int o = 0; o < 31; ++o) sw[lane*33 + o] = acc[o];
        float* gb = out + (size_t)rowbase * ODIM + obase;
#pragma unroll
        for (int it = 0; it < 31; ++it) {
            const int f = it*64 + lane;
            const int row = f / 31;
            const int col = f - row*31;
            gb[row*ODIM + col] = sw[row*33 + col];
        }
    }
}

// ---------------------------------------------------------------------------
extern "C" void kernel_launch(void* const* d_in, const int* in_sizes, int n_in,
                              void* d_out, int out_size, void* d_ws, size_t ws_size,
                              hipStream_t stream) {
    const float* pe     = (const float*)d_in[0];
    const float* ve     = (const float*)d_in[1];
    const float* oe     = (const float*)d_in[2];
    const float* W_pred = (const float*)d_in[3];
    const float* b_pred = (const float*)d_in[4];
    const float* W_bin  = (const float*)d_in[5];
    const float* b_bin  = (const float*)d_in[6];
    const float* W_un   = (const float*)d_in[7];
    const float* b_un   = (const float*)d_in[8];
    const float* W_univ = (const float*)d_in[9];
    const float* b_univ = (const float*)d_in[10];
    const float* W_att  = (const float*)d_in[11];
    const float* b_att  = (const float*)d_in[12];
    const float* W_fin  = (const float*)d_in[13];
    const float* b_fin  = (const float*)d_in[14];
    const int* pred_ids = (const int*)d_in[15];
    const int* var_ids  = (const int*)d_in[16];
    const int* op_ids   = (const int*)d_in[17];
    float* out = (float*)d_out;
    float* ws  = (float*)d_ws;

    precompute_kernel<<<705, 64, 0, stream>>>(pe, ve, oe, W_pred, b_pred,
                                              W_bin, b_bin, W_att, b_att, ws);
    fused_kernel<<<MBIN/512, 512, 0, stream>>>(pe, ve, oe, W_bin, W_un, b_un,
                                               W_univ, b_univ, W_att, b_att,
                                               W_fin, b_fin, pred_ids, var_ids,
                                               op_ids, ws, out);
}

// Round 7
// 672.799 us; speedup vs baseline: 1.6732x; 1.6732x over previous
//
#include <hip/hip_runtime.h>
#include <hip/hip_fp16.h>

#define LDIM 50
#define MBIN 262144
#define ODIM 155
#define VOCABSZ 100

// workspace layout (floats) — produced by precompute_kernel
#define WS_T  0        // 6*100*50 = 30000 : T[s][v][d], s=0 pe-slot (b_pred folded), s=1..5 ve-slots
#define WS_TB 30000    // 100*50 : oe[v] @ W_bin[50:100] + b_bin
#define WS_LG 35000    // 300 : attention logits  [0..99]=pe, [100..199]=ve, [200..299]=oe

// static-LDS layout (floats) for fused kernel
#define O_T   0        // 30000 : T tables   (post-phase1: hA/hB fp16 stash; phase3: transpose)
#define O_PE  30000    // 5000  : pe         (phase2: reused for Tb)
#define O_VE  35000    // 5000  : ve         (phase2: reused for oe)
#define O_LG  40000    // 304   : attention logits
#define LDS_FLOATS 40304   // 161216 B static

// ---------------------------------------------------------------------------
// Precompute vocab-indexed tables (trivial cost, ~2 MFLOP)
// ---------------------------------------------------------------------------
__global__ __launch_bounds__(64) void precompute_kernel(
    const float* __restrict__ pe, const float* __restrict__ ve, const float* __restrict__ oe,
    const float* __restrict__ W_pred, const float* __restrict__ b_pred,
    const float* __restrict__ W_bin, const float* __restrict__ b_bin,
    const float* __restrict__ W_att, const float* __restrict__ b_att,
    float* __restrict__ ws)
{
    const int bid = blockIdx.x;
    const int t = threadIdx.x;
    if (bid < 600) {
        const int s = bid / VOCABSZ, v = bid % VOCABSZ;
        if (t < LDIM) {
            const float* E = (s == 0) ? pe : ve;
            float acc = (s == 0) ? b_pred[t] : 0.0f;
            for (int e = 0; e < LDIM; ++e)
                acc += E[v*LDIM + e] * W_pred[(s*LDIM + e)*LDIM + t];
            ws[WS_T + (s*VOCABSZ + v)*LDIM + t] = acc;
        }
    } else if (bid < 700) {
        const int v = bid - 600;
        if (t < LDIM) {
            float acc = b_bin[t];
            for (int e = 0; e < LDIM; ++e)
                acc += oe[v*LDIM + e] * W_bin[(LDIM + e)*LDIM + t];
            ws[WS_TB + v*LDIM + t] = acc;
        }
    } else {
        const int g = (bid - 700)*64 + t;
        if (g < 300) {
            const int which = g / VOCABSZ, v = g % VOCABSZ;
            const float* E = (which == 0) ? pe : ((which == 1) ? ve : oe);
            float acc = b_att[0];
            for (int e = 0; e < LDIM; ++e)
                acc += E[v*LDIM + e] * W_att[e];
            ws[WS_LG + g] = acc;
        }
    }
}

// ---------------------------------------------------------------------------
// Build h_pred for node with ids (p, v[5]) from LDS tables (round-0 proven).
// Returns exp(h.W_att + b_att).
// ---------------------------------------------------------------------------
__device__ __forceinline__ float build_pred_node_lds(
    int p, const int* v, const float* __restrict__ lds,
    const float* __restrict__ W_att, float batt, float* __restrict__ hout)
{
    const float* lg = lds + O_LG;
    const float e0 = __expf(lg[p]);
    float ek[5];
    float den = e0;
#pragma unroll
    for (int s = 0; s < 5; ++s) { ek[s] = __expf(lg[VOCABSZ + v[s]]); den += ek[s]; }
    const float inv = 1.0f / den;

    const float2* T2  = reinterpret_cast<const float2*>(lds + O_T);
    const float2* pe2 = reinterpret_cast<const float2*>(lds + O_PE);
    const float2* ve2 = reinterpret_cast<const float2*>(lds + O_VE);
    const int rT0 = p*(LDIM/2);
    int rTs[5], rVs[5];
#pragma unroll
    for (int s = 0; s < 5; ++s) {
        rTs[s] = ((s+1)*VOCABSZ + v[s])*(LDIM/2);
        rVs[s] = v[s]*(LDIM/2);
    }

    float l = batt;
#pragma unroll
    for (int i = 0; i < LDIM/2; ++i) {
        float2 lin = T2[rT0 + i];
        float2 pv  = pe2[rT0 + i];
        float nx = e0*pv.x, ny = e0*pv.y;
#pragma unroll
        for (int s = 0; s < 5; ++s) {
            float2 a = T2[rTs[s] + i];
            float2 b = ve2[rVs[s] + i];
            lin.x += a.x; lin.y += a.y;
            nx += ek[s]*b.x; ny += ek[s]*b.y;
        }
        float hx = fmaxf(lin.x, 0.0f) + nx*inv;
        float hy = fmaxf(lin.y, 0.0f) + ny*inv;
        hout[2*i] = hx; hout[2*i+1] = hy;
        l += hx*W_att[2*i] + hy*W_att[2*i+1];
    }
    return __expf(l);
}

// ---------------------------------------------------------------------------
// Fused kernel: one thread per binary node. Round-0 structure, plus:
// after the post-phase-1 barrier, BOTH hA and hB are stashed to fp16 LDS
// ([25][512] __half2 each, in the dead T region; bank-conflict-free).
// Phase-2 live set becomes lin2[50]+temps (~65) -> no spills at the
// allocator's immovable 128-VGPR choice.
// (Round-6 lesson: hot accumulators must be <=~60; round-0 lesson: cold
//  values (hA/hB) spill ~60 floats -> evict them DELIBERATELY to LDS.)
// LDS lifecycle: [T|pe|ve|lg] -> stash over T, Tb/oe over pe/ve ->
// barrier after h_bin -> phase3 transpose over stash region.
// ---------------------------------------------------------------------------
__global__ __launch_bounds__(512)
void fused_kernel(
    const float* __restrict__ pe, const float* __restrict__ ve, const float* __restrict__ oe,
    const float* __restrict__ W_bin,
    const float* __restrict__ W_un, const float* __restrict__ b_un,
    const float* __restrict__ W_univ, const float* __restrict__ b_univ,
    const float* __restrict__ W_att, const float* __restrict__ b_att,
    const float* __restrict__ W_fin, const float* __restrict__ b_fin,
    const int* __restrict__ pred_ids, const int* __restrict__ var_ids,
    const int* __restrict__ op_ids,
    const float* __restrict__ ws, float* __restrict__ out)
{
    __shared__ float lds[LDS_FLOATS];
    const int tid = threadIdx.x;
    const int j = blockIdx.x * 512 + tid;

    // ---- stage T + pe + ve + lg into LDS (coalesced float4) ----
    {
        const float4* src = reinterpret_cast<const float4*>(ws + WS_T);     // 7500 vec4
        float4* dst = reinterpret_cast<float4*>(lds + O_T);
        for (int i = tid; i < 7500; i += 512) dst[i] = src[i];
        const float4* s2 = reinterpret_cast<const float4*>(pe);             // 1250
        float4* d2 = reinterpret_cast<float4*>(lds + O_PE);
        for (int i = tid; i < 1250; i += 512) d2[i] = s2[i];
        const float4* s3 = reinterpret_cast<const float4*>(ve);
        float4* d3 = reinterpret_cast<float4*>(lds + O_VE);
        for (int i = tid; i < 1250; i += 512) d3[i] = s3[i];
        if (tid < 300) lds[O_LG + tid] = ws[WS_LG + tid];
    }
    __syncthreads();

    const float batt = b_att[0];

    // ---- phase 1: build both predicate nodes (regs) ----
    int vA[5], vB[5];
    const int pA = pred_ids[2*j], pB = pred_ids[2*j+1];
#pragma unroll
    for (int s = 0; s < 5; ++s) { vA[s] = var_ids[(2*j)*5 + s]; vB[s] = var_ids[(2*j+1)*5 + s]; }

    float hA[LDIM], hB[LDIM];
    const float w0 = build_pred_node_lds(pA, vA, lds, W_att, batt, hA);
    const float w2 = build_pred_node_lds(pB, vB, lds, W_att, batt, hB);

    const int op = op_ids[j];
    const float w1 = __expf(lds[O_LG + 2*VOCABSZ + op]);
    const float inv2 = 1.0f / (w0 + w1 + w2);

    __syncthreads();   // all phase-1 LDS reads done: T region dead

    // ---- stash hA, hB -> fp16 LDS over dead T region (regs die here) ----
    // stA: half2-offsets [0..12800)   = float [0..12800)
    // stB: half2-offsets [12800..25600) = float [12800..25600)  (< 30000)
    {
        __half2* stA = reinterpret_cast<__half2*>(lds + O_T);
        __half2* stB = stA + 25*512;
#pragma unroll
        for (int i = 0; i < LDIM/2; ++i) {
            stA[i*512 + tid] = __floats2half2_rn(hA[2*i], hA[2*i+1]);
            stB[i*512 + tid] = __floats2half2_rn(hB[2*i], hB[2*i+1]);
        }
    }
    // ---- stage Tb + oe into the (dead) pe/ve region ----
    {
        const float4* src = reinterpret_cast<const float4*>(ws + WS_TB);    // 1250 vec4
        float4* dst = reinterpret_cast<float4*>(lds + O_PE);
        for (int i = tid; i < 1250; i += 512) dst[i] = src[i];
        const float4* s2 = reinterpret_cast<const float4*>(oe);
        float4* d2 = reinterpret_cast<float4*>(lds + O_VE);
        for (int i = tid; i < 1250; i += 512) d2[i] = s2[i];
    }
    __syncthreads();

    const __half2* stA = reinterpret_cast<const __half2*>(lds + O_T);
    const __half2* stB = stA + 25*512;

    // ---- phase 2: lin2 = Tb[op] + hA @ Wbin[0:50] + hB @ Wbin[100:150] ----
    // hA/hB read back from LDS stash: live set = lin2[50] + temps only.
    float lin2[LDIM];
    {
        const float2* Tb2 = reinterpret_cast<const float2*>(lds + O_PE);
        const int r = op*(LDIM/2);
#pragma unroll
        for (int i = 0; i < LDIM/2; ++i) { float2 t2 = Tb2[r+i]; lin2[2*i] = t2.x; lin2[2*i+1] = t2.y; }
    }
#pragma unroll
    for (int i = 0; i < LDIM/2; ++i) {
        const float2 a2 = __half22float2(stA[i*512 + tid]);
        const float2 b2 = __half22float2(stB[i*512 + tid]);
        const float* wa0 = W_bin + (2*i)*LDIM;               // uniform -> s_load stream
        const float* wa1 = W_bin + (2*i+1)*LDIM;
        const float* wb0 = W_bin + (2*LDIM + 2*i)*LDIM;
        const float* wb1 = W_bin + (2*LDIM + 2*i+1)*LDIM;
#pragma unroll
        for (int d = 0; d < LDIM; ++d)
            lin2[d] += a2.x*wa0[d] + a2.y*wa1[d] + b2.x*wb0[d] + b2.y*wb1[d];
    }

    // ---- h_bin = relu(lin2) + inv2*(w0*hA + w2*hB + w1*oe[op]) ----
    float h[LDIM];
    {
        const float2* oe2 = reinterpret_cast<const float2*>(lds + O_VE);
        const int r = op*(LDIM/2);
#pragma unroll
        for (int i = 0; i < LDIM/2; ++i) {
            float2 o2 = oe2[r+i];
            float2 a2 = __half22float2(stA[i*512 + tid]);
            float2 b2 = __half22float2(stB[i*512 + tid]);
            h[2*i]   = fmaxf(lin2[2*i],   0.0f) + (w0*a2.x + w2*b2.x + w1*o2.x)*inv2;
            h[2*i+1] = fmaxf(lin2[2*i+1], 0.0f) + (w0*a2.y + w2*b2.y + w1*o2.y)*inv2;
        }
    }
    __syncthreads();   // all stash reads done: phase-3 overlay is now safe

    // ---- h_un = relu(h @ W_un + b_un); h_q = relu(h_un @ W_univ + b_univ) ----
    {
        float acc[LDIM];
#pragma unroll
        for (int d = 0; d < LDIM; ++d) acc[d] = b_un[d];
#pragma unroll
        for (int e = 0; e < LDIM; ++e) {
            const float he = h[e];
            const float* wr = W_un + e*LDIM;
#pragma unroll
            for (int d = 0; d < LDIM; ++d) acc[d] += he * wr[d];
        }
#pragma unroll
        for (int d = 0; d < LDIM; ++d) h[d] = fmaxf(acc[d], 0.0f);
    }
    {
        float acc[LDIM];
#pragma unroll
        for (int d = 0; d < LDIM; ++d) acc[d] = b_univ[d];
#pragma unroll
        for (int e = 0; e < LDIM; ++e) {
            const float he = h[e];
            const float* wr = W_univ + e*LDIM;
#pragma unroll
            for (int d = 0; d < LDIM; ++d) acc[d] += he * wr[d];
        }
#pragma unroll
        for (int d = 0; d < LDIM; ++d) h[d] = fmaxf(acc[d], 0.0f);
    }

    // ---- phase 3: out row = h @ W_fin + b_fin, LDS-transposed coalesced stores
    //      (per-wave buffer over dead stash region; wave-synchronous, no barrier;
    //       8 waves * 2112 = 16896 floats < 30000-float region)
    const int wave = tid >> 6, lane = tid & 63;
    float* sw = lds + O_T + wave * (64*33);
    const int rowbase = blockIdx.x*512 + wave*64;
    for (int c = 0; c < 5; ++c) {
        float acc[31];
        const int obase = c * 31;
#pragma unroll
        for (int o = 0; o < 31; ++o) acc[o] = b_fin[obase + o];
#pragma unroll
        for (int d = 0; d < LDIM; ++d) {
            const float hq = h[d];
            const float* wr = W_fin + d*ODIM + obase;
#pragma unroll
            for (int o = 0; o < 31; ++o) acc[o] += hq * wr[o];
        }
#pragma unroll
        for (int o = 0; o < 31; ++o) sw[lane*33 + o] = acc[o];
        float* gb = out + (size_t)rowbase * ODIM + obase;
#pragma unroll
        for (int it = 0; it < 31; ++it) {
            const int f = it*64 + lane;
            const int row = f / 31;
            const int col = f - row*31;
            gb[row*ODIM + col] = sw[row*33 + col];
        }
    }
}

// ---------------------------------------------------------------------------
extern "C" void kernel_launch(void* const* d_in, const int* in_sizes, int n_in,
                              void* d_out, int out_size, void* d_ws, size_t ws_size,
                              hipStream_t stream) {
    const float* pe     = (const float*)d_in[0];
    const float* ve     = (const float*)d_in[1];
    const float* oe     = (const float*)d_in[2];
    const float* W_pred = (const float*)d_in[3];
    const float* b_pred = (const float*)d_in[4];
    const float* W_bin  = (const float*)d_in[5];
    const float* b_bin  = (const float*)d_in[6];
    const float* W_un   = (const float*)d_in[7];
    const float* b_un   = (const float*)d_in[8];
    const float* W_univ = (const float*)d_in[9];
    const float* b_univ = (const float*)d_in[10];
    const float* W_att  = (const float*)d_in[11];
    const float* b_att  = (const float*)d_in[12];
    const float* W_fin  = (const float*)d_in[13];
    const float* b_fin  = (const float*)d_in[14];
    const int* pred_ids = (const int*)d_in[15];
    const int* var_ids  = (const int*)d_in[16];
    const int* op_ids   = (const int*)d_in[17];
    float* out = (float*)d_out;
    float* ws  = (float*)d_ws;

    precompute_kernel<<<705, 64, 0, stream>>>(pe, ve, oe, W_pred, b_pred,
                                              W_bin, b_bin, W_att, b_att, ws);
    fused_kernel<<<MBIN/512, 512, 0, stream>>>(pe, ve, oe, W_bin, W_un, b_un,
                                               W_univ, b_univ, W_att, b_att,
                                               W_fin, b_fin, pred_ids, var_ids,
                                               op_ids, ws, out);
}